// Round 3
// baseline (1244.595 us; speedup 1.0000x reference)
//
#include <hip/hip_runtime.h>
#include <math.h>

#define N_ANCH 134400
#define N_CLS  80
#define TOPK   4096
#define MAX_OUT 300

// ---- ws layout (bytes) ----
#define KEYS_OFF   0u         // u64[134400] = 1075200
#define T_OFF      1075200u   // u64
#define CNT_OFF    1075208u   // u32 (+pad)
#define CANDK_OFF  1075216u   // u64[4096] = 32768
#define CBOX_OFF   1107984u   // float4[4096] = 65536 (16B aligned)
#define CSCORE_OFF 1173520u   // f32[4096]
#define CCLS_OFF   1189904u   // i32[4096]
#define SUP_OFF    1206288u   // u64[4096*64] = 2097152
#define WS_NEEDED  3303440u

static __device__ __forceinline__ unsigned int ord_f32(float f) {
  unsigned int u = __float_as_uint(f);
  return (u & 0x80000000u) ? ~u : (u | 0x80000000u);
}
static __device__ __forceinline__ float unord_f32(unsigned int o) {
  unsigned int u = (o & 0x80000000u) ? (o ^ 0x80000000u) : ~o;
  return __uint_as_float(u);
}

// K1: per-anchor score -> 64-bit sort key (score desc, index asc).
// Key order == jax.lax.top_k order (stable: value desc, index asc); keys unique.
__global__ void k_keys(const float* __restrict__ p, unsigned long long* __restrict__ keys) {
  int i = blockIdx.x * blockDim.x + threadIdx.x;
  if (i >= N_ANCH) return;
  float best = p[4 * N_ANCH + i];
#pragma unroll 4
  for (int c = 1; c < N_CLS; ++c) {
    float v = p[(4 + c) * N_ANCH + i];
    best = fmaxf(best, v);
  }
  float m = (best >= 0.25f) ? best : -INFINITY;
  keys[i] = ((unsigned long long)ord_f32(m) << 32) |
            (unsigned long long)(~(unsigned int)i);
}

// K2: exact rank-4096 key via 8x8-bit MSB radix select (single block).
// Leader-aggregated histogram avoids same-address LDS atomic storms
// (scores cluster near 1.0 so bins are heavily skewed).
__global__ __launch_bounds__(1024) void k_select(const unsigned long long* __restrict__ keys,
                                                 unsigned long long* __restrict__ Tout) {
  __shared__ unsigned int cnt[256];
  __shared__ unsigned long long s_pref;
  __shared__ unsigned int s_rank;
  int tid = threadIdx.x, lane = tid & 63;
  if (tid == 0) { s_pref = 0ull; s_rank = TOPK; }
  __syncthreads();
  for (int pass = 0; pass < 8; ++pass) {
    for (int b = tid; b < 256; b += 1024) cnt[b] = 0u;
    __syncthreads();
    int sh = 56 - 8 * pass;
    unsigned long long pref = s_pref;
    for (int i = tid; i < N_ANCH; i += 1024) {
      unsigned long long k = keys[i];
      bool match;
      if (pass == 0) match = true;
      else           match = ((k >> (sh + 8)) == pref);
      unsigned int bin = (unsigned int)(k >> sh) & 255u;
      unsigned long long act = __ballot(match);
      while (act) {
        int leader = __builtin_ctzll(act);
        unsigned int lb = __shfl(bin, leader);
        unsigned long long same = __ballot(match && (bin == lb));
        if (lane == leader) atomicAdd(&cnt[lb], (unsigned int)__builtin_popcountll(same));
        act &= ~same;
      }
    }
    __syncthreads();
    if (tid == 0) {
      unsigned int r = s_rank, cum = 0u;
      int chosen = 0;
      for (int b = 255; b >= 0; --b) {
        unsigned int c = cnt[b];
        if (cum + c >= r) { chosen = b; s_rank = r - cum; break; }
        cum += c;
      }
      s_pref = (pref << 8) | (unsigned long long)(unsigned int)chosen;
    }
    __syncthreads();
  }
  if (tid == 0) *Tout = s_pref;
}

// K3: compact the exactly-4096 keys >= T (unordered; K4 sorts)
__global__ void k_gather(const unsigned long long* __restrict__ keys,
                         const unsigned long long* __restrict__ Tptr,
                         unsigned int* __restrict__ counter,
                         unsigned long long* __restrict__ candk) {
  int i = blockIdx.x * blockDim.x + threadIdx.x;
  if (i >= N_ANCH) return;
  unsigned long long k = keys[i];
  if (k >= *Tptr) {
    unsigned int pos = atomicAdd(counter, 1u);
    if (pos < TOPK) candk[pos] = k;
  }
}

// K4: bitonic sort 4096 keys descending in LDS (exact JAX candidate order)
__global__ __launch_bounds__(1024) void k_sort(unsigned long long* __restrict__ candk) {
  __shared__ unsigned long long s[TOPK];
  for (int i = threadIdx.x; i < TOPK; i += 1024) s[i] = candk[i];
  __syncthreads();
  for (int k = 2; k <= TOPK; k <<= 1) {
    for (int j = k >> 1; j > 0; j >>= 1) {
      for (int i = threadIdx.x; i < TOPK; i += 1024) {
        int ixj = i ^ j;
        if (ixj > i) {
          bool up = ((i & k) == 0);
          unsigned long long a = s[i], b = s[ixj];
          bool sw = up ? (a < b) : (a > b);  // descending overall
          if (sw) { s[i] = b; s[ixj] = a; }
        }
      }
      __syncthreads();
    }
  }
  for (int i = threadIdx.x; i < TOPK; i += 1024) candk[i] = s[i];
}

// K5: decode per-candidate box / class / score (argmax ties -> lowest class,
// matching jnp.argmax; floorf(w*0.5f) == floor(w/2.0) in f32)
__global__ void k_fill(const float* __restrict__ p,
                       const unsigned long long* __restrict__ candk,
                       float4* __restrict__ cbox,
                       float* __restrict__ cscore,
                       int* __restrict__ ccls) {
  int c = blockIdx.x * blockDim.x + threadIdx.x;
  if (c >= TOPK) return;
  unsigned long long k = candk[c];
  float score = unord_f32((unsigned int)(k >> 32));
  int idx = (int)(~(unsigned int)(k & 0xFFFFFFFFull));
  float xc = p[idx];
  float yc = p[N_ANCH + idx];
  float w  = p[2 * N_ANCH + idx];
  float h  = p[3 * N_ANCH + idx];
  float hw = floorf(w * 0.5f), hh = floorf(h * 0.5f);
  cbox[c] = make_float4(xc - hw, yc - hh, xc + hw, yc + hh);
  float best = p[4 * N_ANCH + idx];
  int cls = 0;
  for (int cc = 1; cc < N_CLS; ++cc) {
    float v = p[(4 + cc) * N_ANCH + idx];
    if (v > best) { best = v; cls = cc; }
  }
  cscore[c] = score;
  ccls[c]   = cls;
}

// K6: suppression bitmask matrix, word (row, w) covers j in [w*64, w*64+64).
// IoU arithmetic is op-for-op the reference's (incl. +1e-9f, IEEE division).
__global__ void k_iou(const float4* __restrict__ cbox, unsigned long long* __restrict__ sup) {
  int g = blockIdx.x * blockDim.x + threadIdx.x;  // 4096*64 threads
  int row = g >> 6, word = g & 63;
  float4 bi = cbox[row];
  float ai = (bi.z - bi.x) * (bi.w - bi.y);
  unsigned long long m = 0ull;
  int j0 = word << 6;
  if (j0 + 63 > row) {
    for (int b = 0; b < 64; ++b) {
      int j = j0 + b;
      if (j <= row) continue;
      float4 bj = cbox[j];
      float aj = (bj.z - bj.x) * (bj.w - bj.y);
      float ltx = fmaxf(bi.x, bj.x), lty = fmaxf(bi.y, bj.y);
      float rbx = fminf(bi.z, bj.z), rby = fminf(bi.w, bj.w);
      float ww = fmaxf(rbx - ltx, 0.0f), hh = fmaxf(rby - lty, 0.0f);
      float inter = ww * hh;
      float uni = ai + aj - inter;
      float iou = inter / (uni + 1e-9f);
      if (iou > 0.5f) m |= (1ull << b);
    }
  }
  sup[g] = m;
}

// K7: sequential greedy NMS scan (wave 0, keep-words in registers, ctz-skip
// over kept rows only == the reference fori_loop), then first-300-kept
// compaction + tie/factor/count epilogue. Static LDS ~35KB.
#define CHUNK_ROWS 64
__global__ __launch_bounds__(256) void k_nms_out(const float4* __restrict__ cbox,
                                                 const float* __restrict__ cscore,
                                                 const int* __restrict__ ccls,
                                                 const unsigned long long* __restrict__ sup,
                                                 float* __restrict__ out) {
  __shared__ unsigned long long schunk[CHUNK_ROWS * 64];  // 32KB
  __shared__ unsigned long long skeep[64];
  __shared__ int s_list[MAX_OUT];
  __shared__ float s_fs[MAX_OUT];
  __shared__ int s_K;
  __shared__ int s_cnt;
  int tid = threadIdx.x;
  int lane = tid & 63, wave = tid >> 6;

  unsigned long long kw = 0ull;
  if (wave == 0) {
    for (int b = 0; b < 64; ++b) {
      float sc = cscore[lane * 64 + b];
      if (sc >= 0.25f) kw |= (1ull << b);   // isfinite(masked) == passed threshold
    }
    skeep[lane] = kw;
  }
  if (tid == 0) { s_K = 0; s_cnt = 0; }
  __syncthreads();

  for (int chunk = 0; chunk < TOPK / CHUNK_ROWS; ++chunk) {
    unsigned long long w0 = skeep[chunk];   // uniform read -> uniform branch
    if (w0 == 0ull) continue;               // no kept rows in this chunk
    for (int t = tid; t < CHUNK_ROWS * 64; t += 256)
      schunk[t] = sup[chunk * (CHUNK_ROWS * 64) + t];
    __syncthreads();
    if (wave == 0) {
      int wb = chunk;                        // one keep-word per 64-row chunk
      unsigned long long cur = __shfl(kw, wb);
      while (cur) {
        int b = __builtin_ctzll(cur);
        unsigned long long srow = schunk[b * 64 + lane];
        kw &= ~srow;  // row has only j>i bits; bit i itself survives
        unsigned long long upd = __shfl(kw, wb);
        cur = (b == 63) ? 0ull : (upd & (~0ull << (b + 1)));
      }
      skeep[lane] = kw;
    }
    __syncthreads();
  }

  // compact first 300 kept (candidates are in descending-score order, so
  // final top_k(kept,300) == first 300 kept in order)
  if (tid == 0) {
    int n = 0;
    for (int w = 0; w < 64 && n < MAX_OUT; ++w) {
      unsigned long long m = skeep[w];
      while (m && n < MAX_OUT) {
        int b = __builtin_ctzll(m);
        m &= m - 1ull;
        s_list[n++] = w * 64 + b;
      }
    }
    s_K = n;
  }
  __syncthreads();
  int K = s_K;
  for (int r = tid; r < MAX_OUT; r += 256)
    s_fs[r] = (r < K) ? cscore[s_list[r]] : 0.0f;
  __syncthreads();

  float slast = s_fs[MAX_OUT - 1], sprev = s_fs[MAX_OUT - 2];
  bool tie = fabsf(slast - sprev) < 1e-6f;
  int local = 0;
  for (int r = tid; r < MAX_OUT; r += 256) {
    float fs = s_fs[r];
    float factor = tie ? ((fs - slast > 1e-5f) ? 1.0f : 0.0f) : 1.0f;
    float so = fs * factor;
    out[4 * MAX_OUT + r] = so;          // scores at [1200, 1500)
    if (so > 1e-5f) local++;
    if (r < K) {
      int c = s_list[r];
      float4 b = cbox[c];
      out[4 * r + 0] = b.x / 640.0f;    // boxes at [0, 1200)
      out[4 * r + 1] = b.y / 640.0f;
      out[4 * r + 2] = b.z / 640.0f;
      out[4 * r + 3] = b.w / 640.0f;
      out[5 * MAX_OUT + r] = (float)ccls[c];  // classes at [1500, 1800)
    } else {
      out[4 * r + 0] = 0.0f; out[4 * r + 1] = 0.0f;
      out[4 * r + 2] = 0.0f; out[4 * r + 3] = 0.0f;
      out[5 * MAX_OUT + r] = 0.0f;
    }
  }
  if (local) atomicAdd(&s_cnt, local);
  __syncthreads();
  if (tid == 0) out[6 * MAX_OUT] = (float)s_cnt;  // count at 1800
}

extern "C" void kernel_launch(void* const* d_in, const int* in_sizes, int n_in,
                              void* d_out, int out_size, void* d_ws, size_t ws_size,
                              hipStream_t stream) {
  const float* p = (const float*)d_in[0];
  float* out = (float*)d_out;
  char* ws = (char*)d_ws;

  if (ws_size < (size_t)WS_NEEDED) return;  // fail loudly (validation) not fatally (OOB)

  unsigned long long* keys  = (unsigned long long*)(ws + KEYS_OFF);
  unsigned long long* Tptr  = (unsigned long long*)(ws + T_OFF);
  unsigned int* counter     = (unsigned int*)(ws + CNT_OFF);
  unsigned long long* candk = (unsigned long long*)(ws + CANDK_OFF);
  float4* cbox              = (float4*)(ws + CBOX_OFF);
  float* cscore             = (float*)(ws + CSCORE_OFF);
  int* ccls                 = (int*)(ws + CCLS_OFF);
  unsigned long long* sup   = (unsigned long long*)(ws + SUP_OFF);

  hipMemsetAsync(counter, 0, sizeof(unsigned int), stream);
  k_keys<<<N_ANCH / 256, 256, 0, stream>>>(p, keys);          // 525 blocks
  k_select<<<1, 1024, 0, stream>>>(keys, Tptr);
  k_gather<<<N_ANCH / 256, 256, 0, stream>>>(keys, Tptr, counter, candk);
  k_sort<<<1, 1024, 0, stream>>>(candk);
  k_fill<<<TOPK / 256, 256, 0, stream>>>(p, candk, cbox, cscore, ccls);
  k_iou<<<(TOPK * 64) / 256, 256, 0, stream>>>(cbox, sup);
  k_nms_out<<<1, 256, 0, stream>>>(cbox, cscore, ccls, sup, out);
}

// Round 8
// 687.055 us; speedup vs baseline: 1.8115x; 1.8115x over previous
//
#include <hip/hip_runtime.h>
#include <math.h>

#define N_ANCH 134400
#define N_CLS  80
#define TOPK   4096
#define MAX_OUT 300
#define TIECAP 16384

// ---- ws layout (bytes) ----
#define SARR_OFF   0u          // u32[134400] = 537600
#define GHIST_OFF  537600u     // u32[4][256] = 4096
#define STATE_OFF  541696u     // u32 pref(S* prefix), u32 rank
#define CNT_OFF    541704u     // u32 gather counter
#define TIECNT_OFF 541708u     // u32
#define ISTAR_OFF  541712u     // u32
#define TIEBUF_OFF 541728u     // u32[16384] = 65536
#define CANDK_OFF  607264u     // u64[4096] = 32768
#define CBOX_OFF   640032u     // float4[4096] = 65536 (16B aligned)
#define CSCORE_OFF 705568u     // f32[4096]
#define CCLS_OFF   721952u     // i32[4096]
#define SUP_OFF    738336u     // u64[4096*64] = 2097152
#define WS_NEEDED  2835488u
#define MEMSET_OFF 537600u
#define MEMSET_LEN 4112u       // ghist + state + counter + tiecnt

static __device__ __forceinline__ unsigned int ord_f32(float f) {
  unsigned int u = __float_as_uint(f);
  return (u & 0x80000000u) ? ~u : (u | 0x80000000u);
}
static __device__ __forceinline__ float unord_f32(unsigned int o) {
  unsigned int u = (o & 0x80000000u) ? (o ^ 0x80000000u) : ~o;
  return __uint_as_float(u);
}

// K1: per-anchor max class score -> 32-bit order-preserving key
__global__ void k_keys(const float* __restrict__ p, unsigned int* __restrict__ sarr) {
  int i = blockIdx.x * blockDim.x + threadIdx.x;
  if (i >= N_ANCH) return;
  float best = p[4 * N_ANCH + i];
#pragma unroll 4
  for (int c = 1; c < N_CLS; ++c) {
    float v = p[(4 + c) * N_ANCH + i];
    best = fmaxf(best, v);
  }
  float m = (best >= 0.25f) ? best : -INFINITY;
  sarr[i] = ord_f32(m);
}

// Grid-wide 8-bit MSB radix histogram, pass PASS (shift 24-8*PASS).
template <int PASS>
__global__ __launch_bounds__(256) void k_hist(const unsigned int* __restrict__ sarr,
                                              const unsigned int* __restrict__ state,
                                              unsigned int* __restrict__ ghist) {
  __shared__ unsigned int h[256];
  int tid = threadIdx.x;
  h[tid] = 0u;
  __syncthreads();
  int i = blockIdx.x * 256 + tid;   // grid == N_ANCH exactly (525*256)
  unsigned int s = sarr[i];
  if (PASS == 0) {
    atomicAdd(&h[s >> 24], 1u);
  } else {
    const int sh = 24 - 8 * PASS;   // 16, 8, 0
    if ((s >> (sh + 8)) == state[0])
      atomicAdd(&h[(s >> sh) & 255u], 1u);
  }
  __syncthreads();
  if (h[tid]) atomicAdd(&ghist[PASS * 256 + tid], h[tid]);
}

// Scan 256 bins from top, descend one radix level. state = {pref, rank}.
template <int PASS>
__global__ __launch_bounds__(256) void k_scan(const unsigned int* __restrict__ ghist,
                                              unsigned int* __restrict__ state) {
  __shared__ unsigned int h[256];
  int tid = threadIdx.x;
  h[tid] = ghist[PASS * 256 + tid];
  __syncthreads();
  if (tid == 0) {
    unsigned int r    = (PASS == 0) ? (unsigned)TOPK : state[1];
    unsigned int pref = (PASS == 0) ? 0u : state[0];
    unsigned int cum = 0u;
    for (int b = 255; b >= 0; --b) {
      unsigned int c = h[b];
      if (cum + c >= r) { state[0] = (pref << 8) | (unsigned int)b; state[1] = r - cum; break; }
      cum += c;
    }
  }
}

// Collect indices whose score-key equals S* (exact ties at the cut)
__global__ void k_tiecollect(const unsigned int* __restrict__ sarr,
                             const unsigned int* __restrict__ state,
                             unsigned int* __restrict__ tiecnt,
                             unsigned int* __restrict__ tiebuf) {
  int i = blockIdx.x * 256 + threadIdx.x;
  if (sarr[i] == state[0]) {
    unsigned int pos = atomicAdd(tiecnt, 1u);
    if (pos < TIECAP) tiebuf[pos] = (unsigned int)i;
  }
}

// I* = rank-th smallest index among ties (rank = state[1], 1-based).
__global__ __launch_bounds__(256) void k_tiesel(const unsigned int* __restrict__ state,
                                                const unsigned int* __restrict__ tiecnt,
                                                const unsigned int* __restrict__ tiebuf,
                                                unsigned int* __restrict__ Istar) {
  __shared__ unsigned int buf[TIECAP];  // exactly 64KB static LDS
  unsigned int n = *tiecnt; if (n > TIECAP) n = TIECAP;
  unsigned int rf = state[1];
  for (unsigned int t = threadIdx.x; t < n; t += 256) buf[t] = tiebuf[t];
  __syncthreads();
  for (unsigned int t = threadIdx.x; t < n; t += 256) {
    unsigned int v = buf[t], r = 0u;
    for (unsigned int j = 0; j < n; ++j) r += (buf[j] < v) ? 1u : 0u;
    if (r == rf - 1u) *Istar = v;
  }
}

// K3: gather exactly-4096 selected anchors into 64-bit keys (score desc, idx asc)
__global__ void k_gather(const unsigned int* __restrict__ sarr,
                         const unsigned int* __restrict__ state,
                         const unsigned int* __restrict__ Istar,
                         unsigned int* __restrict__ counter,
                         unsigned long long* __restrict__ candk) {
  int i = blockIdx.x * 256 + threadIdx.x;
  unsigned int s = sarr[i];
  unsigned int S = state[0];
  bool take = (s > S) || (s == S && (unsigned int)i <= *Istar);
  if (take) {
    unsigned int pos = atomicAdd(counter, 1u);
    if (pos < TOPK)
      candk[pos] = ((unsigned long long)s << 32) |
                   (unsigned long long)(~(unsigned int)i);
  }
}

// K4: bitonic sort 4096 keys descending in LDS (exact JAX candidate order)
__global__ __launch_bounds__(1024) void k_sort(unsigned long long* __restrict__ candk) {
  __shared__ unsigned long long s[TOPK];
  for (int i = threadIdx.x; i < TOPK; i += 1024) s[i] = candk[i];
  __syncthreads();
  for (int k = 2; k <= TOPK; k <<= 1) {
    for (int j = k >> 1; j > 0; j >>= 1) {
      for (int i = threadIdx.x; i < TOPK; i += 1024) {
        int ixj = i ^ j;
        if (ixj > i) {
          bool up = ((i & k) == 0);
          unsigned long long a = s[i], b = s[ixj];
          bool sw = up ? (a < b) : (a > b);  // descending overall
          if (sw) { s[i] = b; s[ixj] = a; }
        }
      }
      __syncthreads();
    }
  }
  for (int i = threadIdx.x; i < TOPK; i += 1024) candk[i] = s[i];
}

// K5: decode per-candidate box / class / score
__global__ void k_fill(const float* __restrict__ p,
                       const unsigned long long* __restrict__ candk,
                       float4* __restrict__ cbox,
                       float* __restrict__ cscore,
                       int* __restrict__ ccls) {
  int c = blockIdx.x * blockDim.x + threadIdx.x;
  if (c >= TOPK) return;
  unsigned long long k = candk[c];
  float score = unord_f32((unsigned int)(k >> 32));
  int idx = (int)(~(unsigned int)(k & 0xFFFFFFFFull));
  float xc = p[idx];
  float yc = p[N_ANCH + idx];
  float w  = p[2 * N_ANCH + idx];
  float h  = p[3 * N_ANCH + idx];
  float hw = floorf(w * 0.5f), hh = floorf(h * 0.5f);
  cbox[c] = make_float4(xc - hw, yc - hh, xc + hw, yc + hh);
  float best = p[4 * N_ANCH + idx];
  int cls = 0;
  for (int cc = 1; cc < N_CLS; ++cc) {
    float v = p[(4 + cc) * N_ANCH + idx];
    if (v > best) { best = v; cls = cc; }
  }
  cscore[c] = score;
  ccls[c]   = cls;
}

// K6: suppression bitmask matrix (op-for-op reference IoU, j>i baked in)
__global__ void k_iou(const float4* __restrict__ cbox, unsigned long long* __restrict__ sup) {
  int g = blockIdx.x * blockDim.x + threadIdx.x;  // 4096*64 threads
  int row = g >> 6, word = g & 63;
  float4 bi = cbox[row];
  float ai = (bi.z - bi.x) * (bi.w - bi.y);
  unsigned long long m = 0ull;
  int j0 = word << 6;
  if (j0 + 63 > row) {
    for (int b = 0; b < 64; ++b) {
      int j = j0 + b;
      if (j <= row) continue;
      float4 bj = cbox[j];
      float aj = (bj.z - bj.x) * (bj.w - bj.y);
      float ltx = fmaxf(bi.x, bj.x), lty = fmaxf(bi.y, bj.y);
      float rbx = fminf(bi.z, bj.z), rby = fminf(bi.w, bj.w);
      float ww = fmaxf(rbx - ltx, 0.0f), hh = fmaxf(rby - lty, 0.0f);
      float inter = ww * hh;
      float uni = ai + aj - inter;
      float iou = inter / (uni + 1e-9f);
      if (iou > 0.5f) m |= (1ull << b);
    }
  }
  sup[g] = m;
}

// K7: sequential greedy NMS (== reference fori_loop) + epilogue
#define CHUNK_ROWS 64
__global__ __launch_bounds__(256) void k_nms_out(const float4* __restrict__ cbox,
                                                 const float* __restrict__ cscore,
                                                 const int* __restrict__ ccls,
                                                 const unsigned long long* __restrict__ sup,
                                                 float* __restrict__ out) {
  __shared__ unsigned long long schunk[CHUNK_ROWS * 64];  // 32KB
  __shared__ unsigned long long skeep[64];
  __shared__ int s_list[MAX_OUT];
  __shared__ float s_fs[MAX_OUT];
  __shared__ int s_K;
  __shared__ int s_cnt;
  int tid = threadIdx.x;
  int lane = tid & 63, wave = tid >> 6;

  unsigned long long kw = 0ull;
  if (wave == 0) {
    for (int b = 0; b < 64; ++b) {
      float sc = cscore[lane * 64 + b];
      if (sc >= 0.25f) kw |= (1ull << b);   // isfinite(masked) == passed threshold
    }
    skeep[lane] = kw;
  }
  if (tid == 0) { s_K = 0; s_cnt = 0; }
  __syncthreads();

  for (int chunk = 0; chunk < TOPK / CHUNK_ROWS; ++chunk) {
    unsigned long long w0 = skeep[chunk];   // uniform read -> uniform branch
    if (w0 == 0ull) continue;
    for (int t = tid; t < CHUNK_ROWS * 64; t += 256)
      schunk[t] = sup[chunk * (CHUNK_ROWS * 64) + t];
    __syncthreads();
    if (wave == 0) {
      int wb = chunk;
      unsigned long long cur = __shfl(kw, wb);
      while (cur) {
        int b = __builtin_ctzll(cur);
        unsigned long long srow = schunk[b * 64 + lane];
        kw &= ~srow;  // row has only j>i bits; bit i itself survives
        unsigned long long upd = __shfl(kw, wb);
        cur = (b == 63) ? 0ull : (upd & (~0ull << (b + 1)));
      }
      skeep[lane] = kw;
    }
    __syncthreads();
  }

  if (tid == 0) {
    int n = 0;
    for (int w = 0; w < 64 && n < MAX_OUT; ++w) {
      unsigned long long m = skeep[w];
      while (m && n < MAX_OUT) {
        int b = __builtin_ctzll(m);
        m &= m - 1ull;
        s_list[n++] = w * 64 + b;
      }
    }
    s_K = n;
  }
  __syncthreads();
  int K = s_K;
  for (int r = tid; r < MAX_OUT; r += 256)
    s_fs[r] = (r < K) ? cscore[s_list[r]] : 0.0f;
  __syncthreads();

  float slast = s_fs[MAX_OUT - 1], sprev = s_fs[MAX_OUT - 2];
  bool tie = fabsf(slast - sprev) < 1e-6f;
  int local = 0;
  for (int r = tid; r < MAX_OUT; r += 256) {
    float fs = s_fs[r];
    float factor = tie ? ((fs - slast > 1e-5f) ? 1.0f : 0.0f) : 1.0f;
    float so = fs * factor;
    out[4 * MAX_OUT + r] = so;          // scores at [1200, 1500)
    if (so > 1e-5f) local++;
    if (r < K) {
      int c = s_list[r];
      float4 b = cbox[c];
      out[4 * r + 0] = b.x / 640.0f;    // boxes at [0, 1200)
      out[4 * r + 1] = b.y / 640.0f;
      out[4 * r + 2] = b.z / 640.0f;
      out[4 * r + 3] = b.w / 640.0f;
      out[5 * MAX_OUT + r] = (float)ccls[c];  // classes at [1500, 1800)
    } else {
      out[4 * r + 0] = 0.0f; out[4 * r + 1] = 0.0f;
      out[4 * r + 2] = 0.0f; out[4 * r + 3] = 0.0f;
      out[5 * MAX_OUT + r] = 0.0f;
    }
  }
  if (local) atomicAdd(&s_cnt, local);
  __syncthreads();
  if (tid == 0) out[6 * MAX_OUT] = (float)s_cnt;  // count at 1800
}

extern "C" void kernel_launch(void* const* d_in, const int* in_sizes, int n_in,
                              void* d_out, int out_size, void* d_ws, size_t ws_size,
                              hipStream_t stream) {
  const float* p = (const float*)d_in[0];
  float* out = (float*)d_out;
  char* ws = (char*)d_ws;

  if (ws_size < (size_t)WS_NEEDED) return;

  unsigned int* sarr   = (unsigned int*)(ws + SARR_OFF);
  unsigned int* ghist  = (unsigned int*)(ws + GHIST_OFF);
  unsigned int* state  = (unsigned int*)(ws + STATE_OFF);
  unsigned int* counter= (unsigned int*)(ws + CNT_OFF);
  unsigned int* tiecnt = (unsigned int*)(ws + TIECNT_OFF);
  unsigned int* Istar  = (unsigned int*)(ws + ISTAR_OFF);
  unsigned int* tiebuf = (unsigned int*)(ws + TIEBUF_OFF);
  unsigned long long* candk = (unsigned long long*)(ws + CANDK_OFF);
  float4* cbox              = (float4*)(ws + CBOX_OFF);
  float* cscore             = (float*)(ws + CSCORE_OFF);
  int* ccls                 = (int*)(ws + CCLS_OFF);
  unsigned long long* sup   = (unsigned long long*)(ws + SUP_OFF);

  const int NB = N_ANCH / 256;  // 525, exact

  hipMemsetAsync(ws + MEMSET_OFF, 0, MEMSET_LEN, stream);
  k_keys<<<NB, 256, 0, stream>>>(p, sarr);
  k_hist<0><<<NB, 256, 0, stream>>>(sarr, state, ghist);
  k_scan<0><<<1, 256, 0, stream>>>(ghist, state);
  k_hist<1><<<NB, 256, 0, stream>>>(sarr, state, ghist);
  k_scan<1><<<1, 256, 0, stream>>>(ghist, state);
  k_hist<2><<<NB, 256, 0, stream>>>(sarr, state, ghist);
  k_scan<2><<<1, 256, 0, stream>>>(ghist, state);
  k_hist<3><<<NB, 256, 0, stream>>>(sarr, state, ghist);
  k_scan<3><<<1, 256, 0, stream>>>(ghist, state);
  k_tiecollect<<<NB, 256, 0, stream>>>(sarr, state, tiecnt, tiebuf);
  k_tiesel<<<1, 256, 0, stream>>>(state, tiecnt, tiebuf, Istar);
  k_gather<<<NB, 256, 0, stream>>>(sarr, state, Istar, counter, candk);
  k_sort<<<1, 1024, 0, stream>>>(candk);
  k_fill<<<TOPK / 256, 256, 0, stream>>>(p, candk, cbox, cscore, ccls);
  k_iou<<<(TOPK * 64) / 256, 256, 0, stream>>>(cbox, sup);
  k_nms_out<<<1, 256, 0, stream>>>(cbox, cscore, ccls, sup, out);
}

// Round 9
// 382.287 us; speedup vs baseline: 3.2557x; 1.7972x over previous
//
#include <hip/hip_runtime.h>
#include <math.h>

#define N_ANCH 134400
#define N_CLS  80
#define TOPK   4096
#define MAX_OUT 300
#define TIECAP 16384

// ---- ws layout (bytes) ----
#define SARR_OFF   0u          // u32[134400] = 537600
#define GHIST_OFF  537600u     // u32[4][256] = 4096
#define STATE_OFF  541696u     // u32 pref(S* prefix), u32 rank
#define CNT_OFF    541704u     // u32 gather counter
#define TIECNT_OFF 541708u     // u32
#define ISTAR_OFF  541712u     // u32
#define TIEBUF_OFF 541728u     // u32[16384] = 65536
#define CANDK_OFF  607264u     // u64[4096] = 32768
#define CBOX_OFF   640032u     // float4[4096] = 65536 (16B aligned)
#define CSCORE_OFF 705568u     // f32[4096]
#define CCLS_OFF   721952u     // i32[4096]
#define SUP_OFF    738336u     // u64[4096*64] = 2097152
#define WS_NEEDED  2835488u
#define MEMSET_OFF 537600u
#define MEMSET_LEN 4112u       // ghist + state + counter + tiecnt

static __device__ __forceinline__ unsigned int ord_f32(float f) {
  unsigned int u = __float_as_uint(f);
  return (u & 0x80000000u) ? ~u : (u | 0x80000000u);
}
static __device__ __forceinline__ float unord_f32(unsigned int o) {
  unsigned int u = (o & 0x80000000u) ? (o ^ 0x80000000u) : ~o;
  return __uint_as_float(u);
}

// K1: per-anchor max class score -> 32-bit order-preserving key
__global__ void k_keys(const float* __restrict__ p, unsigned int* __restrict__ sarr) {
  int i = blockIdx.x * blockDim.x + threadIdx.x;
  if (i >= N_ANCH) return;
  float best = p[4 * N_ANCH + i];
#pragma unroll 4
  for (int c = 1; c < N_CLS; ++c) {
    float v = p[(4 + c) * N_ANCH + i];
    best = fmaxf(best, v);
  }
  float m = (best >= 0.25f) ? best : -INFINITY;
  sarr[i] = ord_f32(m);
}

// Grid-wide 8-bit MSB radix histogram, pass PASS (shift 24-8*PASS).
template <int PASS>
__global__ __launch_bounds__(256) void k_hist(const unsigned int* __restrict__ sarr,
                                              const unsigned int* __restrict__ state,
                                              unsigned int* __restrict__ ghist) {
  __shared__ unsigned int h[256];
  int tid = threadIdx.x;
  h[tid] = 0u;
  __syncthreads();
  int i = blockIdx.x * 256 + tid;   // grid == N_ANCH exactly (525*256)
  unsigned int s = sarr[i];
  if (PASS == 0) {
    atomicAdd(&h[s >> 24], 1u);
  } else {
    const int sh = 24 - 8 * PASS;   // 16, 8, 0
    if ((s >> (sh + 8)) == state[0])
      atomicAdd(&h[(s >> sh) & 255u], 1u);
  }
  __syncthreads();
  if (h[tid]) atomicAdd(&ghist[PASS * 256 + tid], h[tid]);
}

// Scan 256 bins from top, descend one radix level. state = {pref, rank}.
template <int PASS>
__global__ __launch_bounds__(256) void k_scan(const unsigned int* __restrict__ ghist,
                                              unsigned int* __restrict__ state) {
  __shared__ unsigned int h[256];
  int tid = threadIdx.x;
  h[tid] = ghist[PASS * 256 + tid];
  __syncthreads();
  if (tid == 0) {
    unsigned int r    = (PASS == 0) ? (unsigned)TOPK : state[1];
    unsigned int pref = (PASS == 0) ? 0u : state[0];
    unsigned int cum = 0u;
    for (int b = 255; b >= 0; --b) {
      unsigned int c = h[b];
      if (cum + c >= r) { state[0] = (pref << 8) | (unsigned int)b; state[1] = r - cum; break; }
      cum += c;
    }
  }
}

// Collect indices whose score-key equals S* (exact ties at the cut)
__global__ void k_tiecollect(const unsigned int* __restrict__ sarr,
                             const unsigned int* __restrict__ state,
                             unsigned int* __restrict__ tiecnt,
                             unsigned int* __restrict__ tiebuf) {
  int i = blockIdx.x * 256 + threadIdx.x;
  if (sarr[i] == state[0]) {
    unsigned int pos = atomicAdd(tiecnt, 1u);
    if (pos < TIECAP) tiebuf[pos] = (unsigned int)i;
  }
}

// I* = rank-th smallest index among ties (rank = state[1], 1-based).
__global__ __launch_bounds__(256) void k_tiesel(const unsigned int* __restrict__ state,
                                                const unsigned int* __restrict__ tiecnt,
                                                const unsigned int* __restrict__ tiebuf,
                                                unsigned int* __restrict__ Istar) {
  __shared__ unsigned int buf[TIECAP];  // exactly 64KB static LDS
  unsigned int n = *tiecnt; if (n > TIECAP) n = TIECAP;
  unsigned int rf = state[1];
  for (unsigned int t = threadIdx.x; t < n; t += 256) buf[t] = tiebuf[t];
  __syncthreads();
  for (unsigned int t = threadIdx.x; t < n; t += 256) {
    unsigned int v = buf[t], r = 0u;
    for (unsigned int j = 0; j < n; ++j) r += (buf[j] < v) ? 1u : 0u;
    if (r == rf - 1u) *Istar = v;
  }
}

// K3: gather exactly-4096 selected anchors into 64-bit keys (score desc, idx asc)
__global__ void k_gather(const unsigned int* __restrict__ sarr,
                         const unsigned int* __restrict__ state,
                         const unsigned int* __restrict__ Istar,
                         unsigned int* __restrict__ counter,
                         unsigned long long* __restrict__ candk) {
  int i = blockIdx.x * 256 + threadIdx.x;
  unsigned int s = sarr[i];
  unsigned int S = state[0];
  bool take = (s > S) || (s == S && (unsigned int)i <= *Istar);
  if (take) {
    unsigned int pos = atomicAdd(counter, 1u);
    if (pos < TOPK)
      candk[pos] = ((unsigned long long)s << 32) |
                   (unsigned long long)(~(unsigned int)i);
  }
}

// K4: bitonic sort 4096 keys descending in LDS (exact JAX candidate order)
__global__ __launch_bounds__(1024) void k_sort(unsigned long long* __restrict__ candk) {
  __shared__ unsigned long long s[TOPK];
  for (int i = threadIdx.x; i < TOPK; i += 1024) s[i] = candk[i];
  __syncthreads();
  for (int k = 2; k <= TOPK; k <<= 1) {
    for (int j = k >> 1; j > 0; j >>= 1) {
      for (int i = threadIdx.x; i < TOPK; i += 1024) {
        int ixj = i ^ j;
        if (ixj > i) {
          bool up = ((i & k) == 0);
          unsigned long long a = s[i], b = s[ixj];
          bool sw = up ? (a < b) : (a > b);  // descending overall
          if (sw) { s[i] = b; s[ixj] = a; }
        }
      }
      __syncthreads();
    }
  }
  for (int i = threadIdx.x; i < TOPK; i += 1024) candk[i] = s[i];
}

// K5: decode per-candidate box / class / score
__global__ void k_fill(const float* __restrict__ p,
                       const unsigned long long* __restrict__ candk,
                       float4* __restrict__ cbox,
                       float* __restrict__ cscore,
                       int* __restrict__ ccls) {
  int c = blockIdx.x * blockDim.x + threadIdx.x;
  if (c >= TOPK) return;
  unsigned long long k = candk[c];
  float score = unord_f32((unsigned int)(k >> 32));
  int idx = (int)(~(unsigned int)(k & 0xFFFFFFFFull));
  float xc = p[idx];
  float yc = p[N_ANCH + idx];
  float w  = p[2 * N_ANCH + idx];
  float h  = p[3 * N_ANCH + idx];
  float hw = floorf(w * 0.5f), hh = floorf(h * 0.5f);
  cbox[c] = make_float4(xc - hw, yc - hh, xc + hw, yc + hh);
  float best = p[4 * N_ANCH + idx];
  int cls = 0;
  for (int cc = 1; cc < N_CLS; ++cc) {
    float v = p[(4 + cc) * N_ANCH + idx];
    if (v > best) { best = v; cls = cc; }
  }
  cscore[c] = score;
  ccls[c]   = cls;
}

// K6: suppression bitmask matrix (op-for-op reference IoU, j>i baked in)
__global__ void k_iou(const float4* __restrict__ cbox, unsigned long long* __restrict__ sup) {
  int g = blockIdx.x * blockDim.x + threadIdx.x;  // 4096*64 threads
  int row = g >> 6, word = g & 63;
  float4 bi = cbox[row];
  float ai = (bi.z - bi.x) * (bi.w - bi.y);
  unsigned long long m = 0ull;
  int j0 = word << 6;
  if (j0 + 63 > row) {
    for (int b = 0; b < 64; ++b) {
      int j = j0 + b;
      if (j <= row) continue;
      float4 bj = cbox[j];
      float aj = (bj.z - bj.x) * (bj.w - bj.y);
      float ltx = fmaxf(bi.x, bj.x), lty = fmaxf(bi.y, bj.y);
      float rbx = fminf(bi.z, bj.z), rby = fminf(bi.w, bj.w);
      float ww = fmaxf(rbx - ltx, 0.0f), hh = fmaxf(rby - lty, 0.0f);
      float inter = ww * hh;
      float uni = ai + aj - inter;
      float iou = inter / (uni + 1e-9f);
      if (iou > 0.5f) m |= (1ull << b);
    }
  }
  sup[g] = m;
}

// K7: sequential greedy NMS with EARLY EXIT at the 300th kept row.
// Legal because the output is exactly the first 300 kept candidates (candidate
// order = score desc; top_k(kept,300) = first-300-kept) and `count` is
// computed only from those 300. Rows past the 300th kept are never observable.
// s_list is built during the scan itself (scan order == kept order).
#define CHUNK_ROWS 64
__global__ __launch_bounds__(256) void k_nms_out(const float4* __restrict__ cbox,
                                                 const float* __restrict__ cscore,
                                                 const int* __restrict__ ccls,
                                                 const unsigned long long* __restrict__ sup,
                                                 float* __restrict__ out) {
  __shared__ unsigned long long schunk[CHUNK_ROWS * 64];  // 32KB
  __shared__ unsigned long long skeep[64];
  __shared__ int s_list[MAX_OUT];
  __shared__ float s_fs[MAX_OUT];
  __shared__ int s_K;
  __shared__ int s_done;
  __shared__ int s_cnt;
  int tid = threadIdx.x;
  int lane = tid & 63, wave = tid >> 6;

  unsigned long long kw = 0ull;
  if (wave == 0) {
    for (int b = 0; b < 64; ++b) {
      float sc = cscore[lane * 64 + b];
      if (sc >= 0.25f) kw |= (1ull << b);   // isfinite(masked) == passed threshold
    }
    skeep[lane] = kw;
  }
  if (tid == 0) { s_K = 0; s_done = 0; s_cnt = 0; }
  __syncthreads();

  for (int chunk = 0; chunk < TOPK / CHUNK_ROWS; ++chunk) {
    if (s_done) break;                      // uniform (read after barrier)
    unsigned long long w0 = skeep[chunk];   // uniform read -> uniform branch
    if (w0 == 0ull) continue;
    for (int t = tid; t < CHUNK_ROWS * 64; t += 256)
      schunk[t] = sup[chunk * (CHUNK_ROWS * 64) + t];
    __syncthreads();
    if (wave == 0) {
      int n = s_K;                           // uniform across wave 0
      unsigned long long cur = __shfl(kw, chunk);
      while (cur) {
        int b = __builtin_ctzll(cur);        // row chunk*64+b is KEPT (final)
        if (lane == 0) s_list[n] = chunk * 64 + b;
        n++;
        if (n == MAX_OUT) { if (lane == 0) s_done = 1; break; }
        unsigned long long srow = schunk[b * 64 + lane];
        kw &= ~srow;  // row has only j>i bits; bit i itself survives
        unsigned long long upd = __shfl(kw, chunk);
        cur = (b == 63) ? 0ull : (upd & (~0ull << (b + 1)));
      }
      if (lane == 0) s_K = n;
      skeep[lane] = kw;
    }
    __syncthreads();
  }

  int K = s_K;
  for (int r = tid; r < MAX_OUT; r += 256)
    s_fs[r] = (r < K) ? cscore[s_list[r]] : 0.0f;
  __syncthreads();

  float slast = s_fs[MAX_OUT - 1], sprev = s_fs[MAX_OUT - 2];
  bool tie = fabsf(slast - sprev) < 1e-6f;
  int local = 0;
  for (int r = tid; r < MAX_OUT; r += 256) {
    float fs = s_fs[r];
    float factor = tie ? ((fs - slast > 1e-5f) ? 1.0f : 0.0f) : 1.0f;
    float so = fs * factor;
    out[4 * MAX_OUT + r] = so;          // scores at [1200, 1500)
    if (so > 1e-5f) local++;
    if (r < K) {
      int c = s_list[r];
      float4 b = cbox[c];
      out[4 * r + 0] = b.x / 640.0f;    // boxes at [0, 1200)
      out[4 * r + 1] = b.y / 640.0f;
      out[4 * r + 2] = b.z / 640.0f;
      out[4 * r + 3] = b.w / 640.0f;
      out[5 * MAX_OUT + r] = (float)ccls[c];  // classes at [1500, 1800)
    } else {
      out[4 * r + 0] = 0.0f; out[4 * r + 1] = 0.0f;
      out[4 * r + 2] = 0.0f; out[4 * r + 3] = 0.0f;
      out[5 * MAX_OUT + r] = 0.0f;
    }
  }
  if (local) atomicAdd(&s_cnt, local);
  __syncthreads();
  if (tid == 0) out[6 * MAX_OUT] = (float)s_cnt;  // count at 1800
}

extern "C" void kernel_launch(void* const* d_in, const int* in_sizes, int n_in,
                              void* d_out, int out_size, void* d_ws, size_t ws_size,
                              hipStream_t stream) {
  const float* p = (const float*)d_in[0];
  float* out = (float*)d_out;
  char* ws = (char*)d_ws;

  if (ws_size < (size_t)WS_NEEDED) return;

  unsigned int* sarr   = (unsigned int*)(ws + SARR_OFF);
  unsigned int* ghist  = (unsigned int*)(ws + GHIST_OFF);
  unsigned int* state  = (unsigned int*)(ws + STATE_OFF);
  unsigned int* counter= (unsigned int*)(ws + CNT_OFF);
  unsigned int* tiecnt = (unsigned int*)(ws + TIECNT_OFF);
  unsigned int* Istar  = (unsigned int*)(ws + ISTAR_OFF);
  unsigned int* tiebuf = (unsigned int*)(ws + TIEBUF_OFF);
  unsigned long long* candk = (unsigned long long*)(ws + CANDK_OFF);
  float4* cbox              = (float4*)(ws + CBOX_OFF);
  float* cscore             = (float*)(ws + CSCORE_OFF);
  int* ccls                 = (int*)(ws + CCLS_OFF);
  unsigned long long* sup   = (unsigned long long*)(ws + SUP_OFF);

  const int NB = N_ANCH / 256;  // 525, exact

  hipMemsetAsync(ws + MEMSET_OFF, 0, MEMSET_LEN, stream);
  k_keys<<<NB, 256, 0, stream>>>(p, sarr);
  k_hist<0><<<NB, 256, 0, stream>>>(sarr, state, ghist);
  k_scan<0><<<1, 256, 0, stream>>>(ghist, state);
  k_hist<1><<<NB, 256, 0, stream>>>(sarr, state, ghist);
  k_scan<1><<<1, 256, 0, stream>>>(ghist, state);
  k_hist<2><<<NB, 256, 0, stream>>>(sarr, state, ghist);
  k_scan<2><<<1, 256, 0, stream>>>(ghist, state);
  k_hist<3><<<NB, 256, 0, stream>>>(sarr, state, ghist);
  k_scan<3><<<1, 256, 0, stream>>>(ghist, state);
  k_tiecollect<<<NB, 256, 0, stream>>>(sarr, state, tiecnt, tiebuf);
  k_tiesel<<<1, 256, 0, stream>>>(state, tiecnt, tiebuf, Istar);
  k_gather<<<NB, 256, 0, stream>>>(sarr, state, Istar, counter, candk);
  k_sort<<<1, 1024, 0, stream>>>(candk);
  k_fill<<<TOPK / 256, 256, 0, stream>>>(p, candk, cbox, cscore, ccls);
  k_iou<<<(TOPK * 64) / 256, 256, 0, stream>>>(cbox, sup);
  k_nms_out<<<1, 256, 0, stream>>>(cbox, cscore, ccls, sup, out);
}